// Round 1
// baseline (897.094 us; speedup 1.0000x reference)
//
#include <hip/hip_runtime.h>
#include <math.h>

#define N_NODES 100000
#define N_EDGES 1600000
#define F_IN 256
#define F_HID 128
#define F_LAT 2
#define VOCAB 100000
#define N_SAMP 512
#define SLOPE 0.2f

#define CHUNK 1024
#define NCHUNK ((N_NODES + CHUNK - 1) / CHUNK)   // 98

// ---------------------------------------------------------------- histogram
__global__ void k_hist(const int* __restrict__ dst, int* __restrict__ deg) {
    int e = blockIdx.x * blockDim.x + threadIdx.x;
    if (e < N_EDGES) atomicAdd(&deg[dst[e]], 1);
}

// ---------------------------------------------------------------- scan (3 kernels)
__global__ void k_chunksum(const int* __restrict__ deg, int* __restrict__ csum) {
    __shared__ int s[256];
    int b = blockIdx.x, t = threadIdx.x;
    int base = b * CHUNK, v = 0;
    for (int i = t; i < CHUNK; i += 256) {
        int idx = base + i;
        if (idx < N_NODES) v += deg[idx];
    }
    s[t] = v; __syncthreads();
    for (int d = 128; d > 0; d >>= 1) { if (t < d) s[t] += s[t + d]; __syncthreads(); }
    if (t == 0) csum[b] = s[0];
}

__global__ void k_serialscan(int* __restrict__ csum, int n) {
    if (blockIdx.x == 0 && threadIdx.x == 0) {
        int acc = 0;
        for (int i = 0; i < n; i++) { int v = csum[i]; csum[i] = acc; acc += v; }
    }
}

__global__ void k_offsets(const int* __restrict__ deg, const int* __restrict__ csum,
                          int* __restrict__ off) {
    __shared__ int sd[CHUNK];
    __shared__ int ss[256];
    int b = blockIdx.x, t = threadIdx.x, base = b * CHUNK;
    for (int i = t; i < CHUNK; i += 256) {
        int idx = base + i;
        sd[i] = (idx < N_NODES) ? deg[idx] : 0;
    }
    __syncthreads();
    int l0 = sd[t * 4], l1 = sd[t * 4 + 1], l2 = sd[t * 4 + 2], l3 = sd[t * 4 + 3];
    int tsum = l0 + l1 + l2 + l3;
    ss[t] = tsum; __syncthreads();
    for (int d = 1; d < 256; d <<= 1) {
        int v = 0;
        if (t >= d) v = ss[t - d];
        __syncthreads();
        ss[t] += v;
        __syncthreads();
    }
    int excl = ss[t] - tsum + csum[b];
    int p0 = excl, p1 = p0 + l0, p2 = p1 + l1, p3 = p2 + l2;
    int idx = base + t * 4;
    if (idx     < N_NODES) off[idx]     = p0;
    if (idx + 1 < N_NODES) off[idx + 1] = p1;
    if (idx + 2 < N_NODES) off[idx + 2] = p2;
    if (idx + 3 < N_NODES) off[idx + 3] = p3;
}

// ---------------------------------------------------------------- GEMM1: h = X @ W1
// 128x128 block tile, BK=32, 256 threads, 8x8 microtile.
#define BM 128
#define BK 32
__launch_bounds__(256)
__global__ void k_gemm1(const float* __restrict__ X, const float* __restrict__ W,
                        float* __restrict__ h) {
    __shared__ float Xs[BM][BK + 1];       // 128 x 33
    __shared__ float Ws[BK][F_HID + 4];    // 32 x 132
    int tid = threadIdx.x;
    int tx = tid & 15;   // col group (8 cols each)
    int ty = tid >> 4;   // row group (8 rows each)
    int row0 = blockIdx.x * BM;

    float acc[8][8];
#pragma unroll
    for (int r = 0; r < 8; r++)
#pragma unroll
        for (int c = 0; c < 8; c++) acc[r][c] = 0.f;

    for (int kb = 0; kb < F_IN; kb += BK) {
#pragma unroll
        for (int i = 0; i < 4; i++) {           // X tile: 128x32 = 1024 float4
            int idx = tid + i * 256;
            int r = idx >> 3;
            int kk = (idx & 7) << 2;
            int grow = row0 + r;
            float4 v = make_float4(0.f, 0.f, 0.f, 0.f);
            if (grow < N_NODES) v = *(const float4*)&X[(size_t)grow * F_IN + kb + kk];
            Xs[r][kk] = v.x; Xs[r][kk + 1] = v.y; Xs[r][kk + 2] = v.z; Xs[r][kk + 3] = v.w;
        }
#pragma unroll
        for (int i = 0; i < 4; i++) {           // W tile: 32x128 = 1024 float4
            int idx = tid + i * 256;
            int kr = idx >> 5;
            int c = (idx & 31) << 2;
            float4 v = *(const float4*)&W[(size_t)(kb + kr) * F_HID + c];
            Ws[kr][c] = v.x; Ws[kr][c + 1] = v.y; Ws[kr][c + 2] = v.z; Ws[kr][c + 3] = v.w;
        }
        __syncthreads();
#pragma unroll
        for (int kk = 0; kk < BK; kk++) {
            float a[8], bb[8];
#pragma unroll
            for (int r = 0; r < 8; r++) a[r] = Xs[ty * 8 + r][kk];
#pragma unroll
            for (int c = 0; c < 8; c++) bb[c] = Ws[kk][tx * 8 + c];
#pragma unroll
            for (int r = 0; r < 8; r++)
#pragma unroll
                for (int c = 0; c < 8; c++) acc[r][c] = fmaf(a[r], bb[c], acc[r][c]);
        }
        __syncthreads();
    }
#pragma unroll
    for (int r = 0; r < 8; r++) {
        int grow = row0 + ty * 8 + r;
        if (grow < N_NODES) {
            float* hp = &h[(size_t)grow * F_HID + tx * 8];
            float4 v0 = {acc[r][0], acc[r][1], acc[r][2], acc[r][3]};
            float4 v1 = {acc[r][4], acc[r][5], acc[r][6], acc[r][7]};
            *(float4*)hp = v0;
            *((float4*)hp + 1) = v1;
        }
    }
}

// ---------------------------------------------------------------- per-node attention scores (layer1)
__global__ void k_escore(const float* __restrict__ h, const float* __restrict__ a_src,
                         const float* __restrict__ a_dst, float* __restrict__ es,
                         float* __restrict__ ed) {
    int node = blockIdx.x * (blockDim.x >> 6) + (threadIdx.x >> 6);
    int lane = threadIdx.x & 63;
    if (node >= N_NODES) return;
    const float* hr = h + (size_t)node * F_HID;
    float x0 = hr[lane], x1 = hr[lane + 64];
    float s = x0 * a_src[lane] + x1 * a_src[lane + 64];
    float d = x0 * a_dst[lane] + x1 * a_dst[lane + 64];
    for (int o = 32; o; o >>= 1) { s += __shfl_down(s, o); d += __shfl_down(d, o); }
    if (lane == 0) { es[node] = s; ed[node] = d; }
}

// ---------------------------------------------------------------- scatter into CSR + leaky_relu score
__global__ void k_scatter(const int* __restrict__ src, const int* __restrict__ dst,
                          const float* __restrict__ es, const float* __restrict__ ed,
                          const int* __restrict__ off, int* __restrict__ cursor,
                          int* __restrict__ src_sorted, float* __restrict__ e1_sorted,
                          int* __restrict__ pos_of_edge) {
    int e = blockIdx.x * blockDim.x + threadIdx.x;
    if (e >= N_EDGES) return;
    int s = src[e], d = dst[e];
    float x = es[s] + ed[d];
    float ev = (x >= 0.f) ? x : SLOPE * x;
    int pos = off[d] + atomicAdd(&cursor[d], 1);
    src_sorted[pos] = s;
    e1_sorted[pos] = ev;
    pos_of_edge[e] = pos;
}

// ---------------------------------------------------------------- layer1 aggregation (wave/node)
__global__ void k_agg1(const float* __restrict__ h, const int* __restrict__ off,
                       const int* __restrict__ deg, const int* __restrict__ src_sorted,
                       const float* __restrict__ e1_sorted, float* __restrict__ h1) {
    int node = blockIdx.x * (blockDim.x >> 6) + (threadIdx.x >> 6);
    int lane = threadIdx.x & 63;
    if (node >= N_NODES) return;
    int start = off[node], n = deg[node];
    float m = -INFINITY;
    for (int i = lane; i < n; i += 64) m = fmaxf(m, e1_sorted[start + i]);
    for (int o = 32; o; o >>= 1) m = fmaxf(m, __shfl_down(m, o));
    m = __shfl(m, 0);
    float ssum = 0.f;
    for (int i = lane; i < n; i += 64) ssum += __expf(e1_sorted[start + i] - m);
    for (int o = 32; o; o >>= 1) ssum += __shfl_down(ssum, o);
    ssum = __shfl(ssum, 0);
    float inv = 1.f / fmaxf(ssum, 1e-16f);
    float a0 = 0.f, a1 = 0.f;
    for (int i = 0; i < n; i++) {
        int s = src_sorted[start + i];
        float w = __expf(e1_sorted[start + i] - m) * inv;
        const float* hr = h + (size_t)s * F_HID;
        a0 = fmaf(w, hr[lane], a0);
        a1 = fmaf(w, hr[lane + 64], a1);
    }
    float* o = h1 + (size_t)node * F_HID;
    o[lane] = fmaxf(a0, 0.f);        // fused relu (encoder layer 1)
    o[lane + 64] = fmaxf(a1, 0.f);
}

// ---------------------------------------------------------------- layer2 GEMV + scores (wave/node)
__global__ void k_l2(const float* __restrict__ h1, const float* __restrict__ W_mu,
                     const float* __restrict__ amu_src, const float* __restrict__ amu_dst,
                     float* __restrict__ h2, float* __restrict__ e2s, float* __restrict__ e2d) {
    int node = blockIdx.x * (blockDim.x >> 6) + (threadIdx.x >> 6);
    int lane = threadIdx.x & 63;
    if (node >= N_NODES) return;
    const float* hr = h1 + (size_t)node * F_HID;
    float x0 = hr[lane], x1 = hr[lane + 64];
    float p0 = x0 * W_mu[lane * 2] + x1 * W_mu[(lane + 64) * 2];
    float p1 = x0 * W_mu[lane * 2 + 1] + x1 * W_mu[(lane + 64) * 2 + 1];
    for (int o = 32; o; o >>= 1) { p0 += __shfl_down(p0, o); p1 += __shfl_down(p1, o); }
    if (lane == 0) {
        h2[node * 2] = p0;
        h2[node * 2 + 1] = p1;
        e2s[node] = p0 * amu_src[0] + p1 * amu_src[1];
        e2d[node] = p0 * amu_dst[0] + p1 * amu_dst[1];
    }
}

// ---------------------------------------------------------------- layer2 edge scores into sorted order
__global__ void k_edge2(const int* __restrict__ src, const int* __restrict__ dst,
                        const float* __restrict__ e2s, const float* __restrict__ e2d,
                        const int* __restrict__ pos_of_edge, float* __restrict__ e2_sorted) {
    int e = blockIdx.x * blockDim.x + threadIdx.x;
    if (e >= N_EDGES) return;
    float x = e2s[src[e]] + e2d[dst[e]];
    float v = (x >= 0.f) ? x : SLOPE * x;
    e2_sorted[pos_of_edge[e]] = v;
}

// ---------------------------------------------------------------- layer2 aggregation (thread/node) -> mu
__global__ void k_agg2(const float* __restrict__ h2, const int* __restrict__ off,
                       const int* __restrict__ deg, const int* __restrict__ src_sorted,
                       const float* __restrict__ e2_sorted, float* __restrict__ mu_out) {
    int node = blockIdx.x * blockDim.x + threadIdx.x;
    if (node >= N_NODES) return;
    int start = off[node], n = deg[node];
    float m = -INFINITY;
    for (int i = 0; i < n; i++) m = fmaxf(m, e2_sorted[start + i]);
    float ssum = 0.f;
    for (int i = 0; i < n; i++) ssum += __expf(e2_sorted[start + i] - m);
    float inv = 1.f / fmaxf(ssum, 1e-16f);
    float a0 = 0.f, a1 = 0.f;
    for (int i = 0; i < n; i++) {
        float w = __expf(e2_sorted[start + i] - m) * inv;
        int s = src_sorted[start + i];
        a0 = fmaf(w, h2[s * 2], a0);
        a1 = fmaf(w, h2[s * 2 + 1], a1);
    }
    mu_out[node * 2] = a0;
    mu_out[node * 2 + 1] = a1;
}

// ---------------------------------------------------------------- sampled-softmax logits
__global__ void k_logits(const float* __restrict__ mu, const int* __restrict__ input_y,
                         const int* __restrict__ sample_ids, const float* __restrict__ ssw,
                         const float* __restrict__ ssb, float* __restrict__ out) {
    __shared__ float sw0[N_SAMP], sw1[N_SAMP], sb[N_SAMP];
    int t = threadIdx.x;
    for (int i = t; i < N_SAMP; i += blockDim.x) {
        int sid = sample_ids[i];
        sw0[i] = ssw[sid * 2];
        sw1[i] = ssw[sid * 2 + 1];
        sb[i] = ssb[sid];
    }
    __syncthreads();
    int n0 = blockIdx.x * 8;
    for (int k = 0; k < 8; k++) {
        int node = n0 + k;
        if (node >= N_NODES) break;
        float m0 = mu[node * 2], m1 = mu[node * 2 + 1];
        float* orow = out + (size_t)node * (N_SAMP + 1);
        for (int j = t; j < N_SAMP + 1; j += blockDim.x) {
            float v;
            if (j == 0) {
                int y = input_y[node];
                v = m0 * ssw[y * 2] + m1 * ssw[y * 2 + 1] + ssb[y];
            } else {
                v = m0 * sw0[j - 1] + m1 * sw1[j - 1] + sb[j - 1];
            }
            orow[j] = v;
        }
    }
}

// ================================================================ launch
extern "C" void kernel_launch(void* const* d_in, const int* in_sizes, int n_in,
                              void* d_out, int out_size, void* d_ws, size_t ws_size,
                              hipStream_t stream) {
    const float* X          = (const float*)d_in[0];
    const int*   input_y    = (const int*)d_in[2];
    const int*   edge_index = (const int*)d_in[3];
    const int*   sample_ids = (const int*)d_in[4];
    const float* W1         = (const float*)d_in[5];
    const float* a1_src     = (const float*)d_in[6];
    const float* a1_dst     = (const float*)d_in[7];
    const float* W_mu       = (const float*)d_in[8];
    const float* amu_src    = (const float*)d_in[9];
    const float* amu_dst    = (const float*)d_in[10];
    const float* ssw        = (const float*)d_in[14];
    const float* ssb        = (const float*)d_in[15];
    const int* src = edge_index;
    const int* dst = edge_index + N_EDGES;
    float* out = (float*)d_out;

    // workspace carve-up
    char* ws = (char*)d_ws;
    size_t o = 0;
    float* h        = (float*)(ws + o); o += (size_t)N_NODES * F_HID * 4;   // 51.2 MB
    float* h1       = (float*)(ws + o); o += (size_t)N_NODES * F_HID * 4;   // 51.2 MB
    float* es       = (float*)(ws + o); o += (size_t)N_NODES * 4;
    float* ed       = (float*)(ws + o); o += (size_t)N_NODES * 4;
    float* e2s      = (float*)(ws + o); o += (size_t)N_NODES * 4;
    float* e2d      = (float*)(ws + o); o += (size_t)N_NODES * 4;
    float* h2       = (float*)(ws + o); o += (size_t)N_NODES * F_LAT * 4;
    int*   deg      = (int*)(ws + o);   o += (size_t)N_NODES * 4;
    int*   off      = (int*)(ws + o);   o += (size_t)N_NODES * 4;
    int*   cursor   = (int*)(ws + o);   o += (size_t)N_NODES * 4;
    int*   csum     = (int*)(ws + o);   o += 128 * 4;
    int*   src_sorted  = (int*)(ws + o);   o += (size_t)N_EDGES * 4;
    float* e1_sorted   = (float*)(ws + o); o += (size_t)N_EDGES * 4;
    int*   pos_of_edge = (int*)(ws + o);   o += (size_t)N_EDGES * 4;
    float* e2_sorted   = (float*)(ws + o); o += (size_t)N_EDGES * 4;
    // mu lives directly in d_out tail
    float* mu = out + (size_t)N_NODES * (N_SAMP + 1);

    hipMemsetAsync(deg, 0, (size_t)N_NODES * 4, stream);
    hipMemsetAsync(cursor, 0, (size_t)N_NODES * 4, stream);

    const int EB = (N_EDGES + 255) / 256;          // 6250
    const int WPN = (N_NODES + 3) / 4;             // 25000 (4 waves/block, wave per node)
    const int NB = (N_NODES + 255) / 256;          // 391

    k_hist<<<EB, 256, 0, stream>>>(dst, deg);
    k_chunksum<<<NCHUNK, 256, 0, stream>>>(deg, csum);
    k_serialscan<<<1, 64, 0, stream>>>(csum, NCHUNK);
    k_offsets<<<NCHUNK, 256, 0, stream>>>(deg, csum, off);

    k_gemm1<<<(N_NODES + BM - 1) / BM, 256, 0, stream>>>(X, W1, h);
    k_escore<<<WPN, 256, 0, stream>>>(h, a1_src, a1_dst, es, ed);
    k_scatter<<<EB, 256, 0, stream>>>(src, dst, es, ed, off, cursor,
                                      src_sorted, e1_sorted, pos_of_edge);
    k_agg1<<<WPN, 256, 0, stream>>>(h, off, deg, src_sorted, e1_sorted, h1);

    k_l2<<<WPN, 256, 0, stream>>>(h1, W_mu, amu_src, amu_dst, h2, e2s, e2d);
    k_edge2<<<EB, 256, 0, stream>>>(src, dst, e2s, e2d, pos_of_edge, e2_sorted);
    k_agg2<<<NB, 256, 0, stream>>>(h2, off, deg, src_sorted, e2_sorted, mu);

    k_logits<<<(N_NODES + 7) / 8, 256, 0, stream>>>(mu, input_y, sample_ids, ssw, ssb, out);
}

// Round 2
// 824.304 us; speedup vs baseline: 1.0883x; 1.0883x over previous
//
#include <hip/hip_runtime.h>
#include <math.h>

#define N_NODES 100000
#define N_EDGES 1600000
#define F_IN 256
#define F_HID 128
#define F_LAT 2
#define VOCAB 100000
#define N_SAMP 512
#define SLOPE 0.2f

#define CHUNK 1024
#define NCHUNK ((N_NODES + CHUNK - 1) / CHUNK)   // 98

// ---------------------------------------------------------------- histogram
__global__ void k_hist(const int* __restrict__ dst, int* __restrict__ deg) {
    int e = blockIdx.x * blockDim.x + threadIdx.x;
    if (e < N_EDGES) atomicAdd(&deg[dst[e]], 1);
}

// ---------------------------------------------------------------- scan (3 kernels)
__global__ void k_chunksum(const int* __restrict__ deg, int* __restrict__ csum) {
    __shared__ int s[256];
    int b = blockIdx.x, t = threadIdx.x;
    int base = b * CHUNK, v = 0;
    for (int i = t; i < CHUNK; i += 256) {
        int idx = base + i;
        if (idx < N_NODES) v += deg[idx];
    }
    s[t] = v; __syncthreads();
    for (int d = 128; d > 0; d >>= 1) { if (t < d) s[t] += s[t + d]; __syncthreads(); }
    if (t == 0) csum[b] = s[0];
}

// single-block LDS scan over the 98 chunk sums (replaces 1-thread serial scan)
__global__ void k_scan98(int* __restrict__ csum) {
    __shared__ int s[128];
    int t = threadIdx.x;
    int v = (t < NCHUNK) ? csum[t] : 0;
    s[t] = v; __syncthreads();
    for (int d = 1; d < 128; d <<= 1) {
        int u = (t >= d) ? s[t - d] : 0;
        __syncthreads();
        s[t] += u;
        __syncthreads();
    }
    if (t < NCHUNK) csum[t] = s[t] - v;   // exclusive prefix
}

__global__ void k_offsets(const int* __restrict__ deg, const int* __restrict__ csum,
                          int* __restrict__ off) {
    __shared__ int sd[CHUNK];
    __shared__ int ss[256];
    int b = blockIdx.x, t = threadIdx.x, base = b * CHUNK;
    for (int i = t; i < CHUNK; i += 256) {
        int idx = base + i;
        sd[i] = (idx < N_NODES) ? deg[idx] : 0;
    }
    __syncthreads();
    int l0 = sd[t * 4], l1 = sd[t * 4 + 1], l2 = sd[t * 4 + 2], l3 = sd[t * 4 + 3];
    int tsum = l0 + l1 + l2 + l3;
    ss[t] = tsum; __syncthreads();
    for (int d = 1; d < 256; d <<= 1) {
        int v = 0;
        if (t >= d) v = ss[t - d];
        __syncthreads();
        ss[t] += v;
        __syncthreads();
    }
    int excl = ss[t] - tsum + csum[b];
    int p0 = excl, p1 = p0 + l0, p2 = p1 + l1, p3 = p2 + l2;
    int idx = base + t * 4;
    if (idx     < N_NODES) off[idx]     = p0;
    if (idx + 1 < N_NODES) off[idx + 1] = p1;
    if (idx + 2 < N_NODES) off[idx + 2] = p2;
    if (idx + 3 < N_NODES) off[idx + 3] = p3;
}

// ---------------------------------------------------------------- GEMM1: h = X @ W1
#define BM 128
#define BK 32
__launch_bounds__(256)
__global__ void k_gemm1(const float* __restrict__ X, const float* __restrict__ W,
                        float* __restrict__ h) {
    __shared__ float Xs[BM][BK + 1];
    __shared__ float Ws[BK][F_HID + 4];
    int tid = threadIdx.x;
    int tx = tid & 15;
    int ty = tid >> 4;
    int row0 = blockIdx.x * BM;

    float acc[8][8];
#pragma unroll
    for (int r = 0; r < 8; r++)
#pragma unroll
        for (int c = 0; c < 8; c++) acc[r][c] = 0.f;

    for (int kb = 0; kb < F_IN; kb += BK) {
#pragma unroll
        for (int i = 0; i < 4; i++) {
            int idx = tid + i * 256;
            int r = idx >> 3;
            int kk = (idx & 7) << 2;
            int grow = row0 + r;
            float4 v = make_float4(0.f, 0.f, 0.f, 0.f);
            if (grow < N_NODES) v = *(const float4*)&X[(size_t)grow * F_IN + kb + kk];
            Xs[r][kk] = v.x; Xs[r][kk + 1] = v.y; Xs[r][kk + 2] = v.z; Xs[r][kk + 3] = v.w;
        }
#pragma unroll
        for (int i = 0; i < 4; i++) {
            int idx = tid + i * 256;
            int kr = idx >> 5;
            int c = (idx & 31) << 2;
            float4 v = *(const float4*)&W[(size_t)(kb + kr) * F_HID + c];
            Ws[kr][c] = v.x; Ws[kr][c + 1] = v.y; Ws[kr][c + 2] = v.z; Ws[kr][c + 3] = v.w;
        }
        __syncthreads();
#pragma unroll
        for (int kk = 0; kk < BK; kk++) {
            float a[8], bb[8];
#pragma unroll
            for (int r = 0; r < 8; r++) a[r] = Xs[ty * 8 + r][kk];
#pragma unroll
            for (int c = 0; c < 8; c++) bb[c] = Ws[kk][tx * 8 + c];
#pragma unroll
            for (int r = 0; r < 8; r++)
#pragma unroll
                for (int c = 0; c < 8; c++) acc[r][c] = fmaf(a[r], bb[c], acc[r][c]);
        }
        __syncthreads();
    }
#pragma unroll
    for (int r = 0; r < 8; r++) {
        int grow = row0 + ty * 8 + r;
        if (grow < N_NODES) {
            float* hp = &h[(size_t)grow * F_HID + tx * 8];
            float4 v0 = {acc[r][0], acc[r][1], acc[r][2], acc[r][3]};
            float4 v1 = {acc[r][4], acc[r][5], acc[r][6], acc[r][7]};
            *(float4*)hp = v0;
            *((float4*)hp + 1) = v1;
        }
    }
}

// ---------------------------------------------------------------- per-node attention scores (layer1)
__global__ void k_escore(const float* __restrict__ h, const float* __restrict__ a_src,
                         const float* __restrict__ a_dst, float* __restrict__ es,
                         float* __restrict__ ed) {
    int node = blockIdx.x * (blockDim.x >> 6) + (threadIdx.x >> 6);
    int lane = threadIdx.x & 63;
    if (node >= N_NODES) return;
    const float* hr = h + (size_t)node * F_HID;
    float x0 = hr[lane], x1 = hr[lane + 64];
    float s = x0 * a_src[lane] + x1 * a_src[lane + 64];
    float d = x0 * a_dst[lane] + x1 * a_dst[lane + 64];
    for (int o = 32; o; o >>= 1) { s += __shfl_down(s, o); d += __shfl_down(d, o); }
    if (lane == 0) { es[node] = s; ed[node] = d; }
}

// ---------------------------------------------------------------- scatter into CSR + leaky_relu score
__global__ void k_scatter(const int* __restrict__ src, const int* __restrict__ dst,
                          const float* __restrict__ es, const float* __restrict__ ed,
                          const int* __restrict__ off, int* __restrict__ cursor,
                          int* __restrict__ src_sorted, float* __restrict__ e1_sorted,
                          int* __restrict__ pos_of_edge) {
    int e = blockIdx.x * blockDim.x + threadIdx.x;
    if (e >= N_EDGES) return;
    int s = src[e], d = dst[e];
    float x = es[s] + ed[d];
    float ev = (x >= 0.f) ? x : SLOPE * x;
    int pos = off[d] + atomicAdd(&cursor[d], 1);
    src_sorted[pos] = s;
    e1_sorted[pos] = ev;
    pos_of_edge[e] = pos;
}

// ---------------------------------------------------------------- layer1 aggregation (wave/node)
// lane i owns h columns [2i, 2i+1] (one float2 = 512B/row/wave in one instr).
// Pass 1: wave max. Pass 2: fused unnormalized gather + denom, x4 unrolled for ILP.
__global__ void k_agg1(const float* __restrict__ h, const int* __restrict__ off,
                       const int* __restrict__ deg, const int* __restrict__ src_sorted,
                       const float* __restrict__ e1_sorted, float* __restrict__ h1) {
    int node = blockIdx.x * (blockDim.x >> 6) + (threadIdx.x >> 6);
    int lane = threadIdx.x & 63;
    if (node >= N_NODES) return;
    int start = off[node], n = deg[node];
    const int* sp = src_sorted + start;
    const float* ep = e1_sorted + start;

    float m = -INFINITY;
    for (int i = lane; i < n; i += 64) m = fmaxf(m, ep[i]);
#pragma unroll
    for (int o = 32; o; o >>= 1) m = fmaxf(m, __shfl_xor(m, o));

    const float* hb = h + 2 * lane;
    float a0 = 0.f, a1 = 0.f, ssum = 0.f;
    int i = 0;
    for (; i + 4 <= n; i += 4) {
        int s0 = sp[i], s1 = sp[i + 1], s2 = sp[i + 2], s3 = sp[i + 3];
        float w0 = __expf(ep[i] - m);
        float w1 = __expf(ep[i + 1] - m);
        float w2 = __expf(ep[i + 2] - m);
        float w3 = __expf(ep[i + 3] - m);
        float2 r0 = *(const float2*)(hb + (size_t)s0 * F_HID);
        float2 r1 = *(const float2*)(hb + (size_t)s1 * F_HID);
        float2 r2 = *(const float2*)(hb + (size_t)s2 * F_HID);
        float2 r3 = *(const float2*)(hb + (size_t)s3 * F_HID);
        ssum += (w0 + w1) + (w2 + w3);
        a0 = fmaf(w0, r0.x, a0); a1 = fmaf(w0, r0.y, a1);
        a0 = fmaf(w1, r1.x, a0); a1 = fmaf(w1, r1.y, a1);
        a0 = fmaf(w2, r2.x, a0); a1 = fmaf(w2, r2.y, a1);
        a0 = fmaf(w3, r3.x, a0); a1 = fmaf(w3, r3.y, a1);
    }
    for (; i < n; i++) {
        int s = sp[i];
        float w = __expf(ep[i] - m);
        float2 r = *(const float2*)(hb + (size_t)s * F_HID);
        ssum += w;
        a0 = fmaf(w, r.x, a0); a1 = fmaf(w, r.y, a1);
    }
    float inv = 1.f / fmaxf(ssum, 1e-16f);
    float2 outv = {fmaxf(a0 * inv, 0.f), fmaxf(a1 * inv, 0.f)};   // fused relu
    *(float2*)(h1 + (size_t)node * F_HID + 2 * lane) = outv;
}

// ---------------------------------------------------------------- layer2 GEMV + scores (wave/node)
__global__ void k_l2(const float* __restrict__ h1, const float* __restrict__ W_mu,
                     const float* __restrict__ amu_src, const float* __restrict__ amu_dst,
                     float* __restrict__ h2, float* __restrict__ e2s, float* __restrict__ e2d) {
    int node = blockIdx.x * (blockDim.x >> 6) + (threadIdx.x >> 6);
    int lane = threadIdx.x & 63;
    if (node >= N_NODES) return;
    const float* hr = h1 + (size_t)node * F_HID;
    float x0 = hr[lane], x1 = hr[lane + 64];
    float p0 = x0 * W_mu[lane * 2] + x1 * W_mu[(lane + 64) * 2];
    float p1 = x0 * W_mu[lane * 2 + 1] + x1 * W_mu[(lane + 64) * 2 + 1];
    for (int o = 32; o; o >>= 1) { p0 += __shfl_down(p0, o); p1 += __shfl_down(p1, o); }
    if (lane == 0) {
        h2[node * 2] = p0;
        h2[node * 2 + 1] = p1;
        e2s[node] = p0 * amu_src[0] + p1 * amu_src[1];
        e2d[node] = p0 * amu_dst[0] + p1 * amu_dst[1];
    }
}

// ---------------------------------------------------------------- layer2 edge scores into sorted order
__global__ void k_edge2(const int* __restrict__ src, const int* __restrict__ dst,
                        const float* __restrict__ e2s, const float* __restrict__ e2d,
                        const int* __restrict__ pos_of_edge, float* __restrict__ e2_sorted) {
    int e = blockIdx.x * blockDim.x + threadIdx.x;
    if (e >= N_EDGES) return;
    float x = e2s[src[e]] + e2d[dst[e]];
    float v = (x >= 0.f) ? x : SLOPE * x;
    e2_sorted[pos_of_edge[e]] = v;
}

// ---------------------------------------------------------------- layer2 aggregation: 16-lane segment per node
__global__ void k_agg2(const float* __restrict__ h2, const int* __restrict__ off,
                       const int* __restrict__ deg, const int* __restrict__ src_sorted,
                       const float* __restrict__ e2_sorted, float* __restrict__ mu_out) {
    int node = blockIdx.x * (blockDim.x >> 4) + (threadIdx.x >> 4);
    int lane = threadIdx.x & 15;
    if (node >= N_NODES) return;
    int start = off[node], n = deg[node];
    float m = -INFINITY;
    for (int i = lane; i < n; i += 16) m = fmaxf(m, e2_sorted[start + i]);
#pragma unroll
    for (int o = 8; o; o >>= 1) m = fmaxf(m, __shfl_xor(m, o, 16));
    float s = 0.f, a0 = 0.f, a1 = 0.f;
    for (int i = lane; i < n; i += 16) {
        float w = __expf(e2_sorted[start + i] - m);
        int sidx = src_sorted[start + i];
        s += w;
        a0 = fmaf(w, h2[sidx * 2], a0);
        a1 = fmaf(w, h2[sidx * 2 + 1], a1);
    }
#pragma unroll
    for (int o = 8; o; o >>= 1) {
        s  += __shfl_xor(s, o, 16);
        a0 += __shfl_xor(a0, o, 16);
        a1 += __shfl_xor(a1, o, 16);
    }
    if (lane == 0) {
        float inv = 1.f / fmaxf(s, 1e-16f);
        float2 v = {a0 * inv, a1 * inv};
        *(float2*)(mu_out + node * 2) = v;
    }
}

// ---------------------------------------------------------------- sampled-softmax logits
__global__ void k_logits(const float* __restrict__ mu, const int* __restrict__ input_y,
                         const int* __restrict__ sample_ids, const float* __restrict__ ssw,
                         const float* __restrict__ ssb, float* __restrict__ out) {
    __shared__ float sw0[N_SAMP], sw1[N_SAMP], sb[N_SAMP];
    int t = threadIdx.x;
    for (int i = t; i < N_SAMP; i += blockDim.x) {
        int sid = sample_ids[i];
        sw0[i] = ssw[sid * 2];
        sw1[i] = ssw[sid * 2 + 1];
        sb[i] = ssb[sid];
    }
    __syncthreads();
    int n0 = blockIdx.x * 8;
    for (int k = 0; k < 8; k++) {
        int node = n0 + k;
        if (node >= N_NODES) break;
        float m0 = mu[node * 2], m1 = mu[node * 2 + 1];
        float* orow = out + (size_t)node * (N_SAMP + 1);
        for (int j = t; j < N_SAMP + 1; j += blockDim.x) {
            float v;
            if (j == 0) {
                int y = input_y[node];
                v = m0 * ssw[y * 2] + m1 * ssw[y * 2 + 1] + ssb[y];
            } else {
                v = m0 * sw0[j - 1] + m1 * sw1[j - 1] + sb[j - 1];
            }
            orow[j] = v;
        }
    }
}

// ================================================================ launch
extern "C" void kernel_launch(void* const* d_in, const int* in_sizes, int n_in,
                              void* d_out, int out_size, void* d_ws, size_t ws_size,
                              hipStream_t stream) {
    const float* X          = (const float*)d_in[0];
    const int*   input_y    = (const int*)d_in[2];
    const int*   edge_index = (const int*)d_in[3];
    const int*   sample_ids = (const int*)d_in[4];
    const float* W1         = (const float*)d_in[5];
    const float* a1_src     = (const float*)d_in[6];
    const float* a1_dst     = (const float*)d_in[7];
    const float* W_mu       = (const float*)d_in[8];
    const float* amu_src    = (const float*)d_in[9];
    const float* amu_dst    = (const float*)d_in[10];
    const float* ssw        = (const float*)d_in[14];
    const float* ssb        = (const float*)d_in[15];
    const int* src = edge_index;
    const int* dst = edge_index + N_EDGES;
    float* out = (float*)d_out;

    char* ws = (char*)d_ws;
    size_t o = 0;
    float* h        = (float*)(ws + o); o += (size_t)N_NODES * F_HID * 4;
    float* h1       = (float*)(ws + o); o += (size_t)N_NODES * F_HID * 4;
    float* es       = (float*)(ws + o); o += (size_t)N_NODES * 4;
    float* ed       = (float*)(ws + o); o += (size_t)N_NODES * 4;
    float* e2s      = (float*)(ws + o); o += (size_t)N_NODES * 4;
    float* e2d      = (float*)(ws + o); o += (size_t)N_NODES * 4;
    float* h2       = (float*)(ws + o); o += (size_t)N_NODES * F_LAT * 4;
    int*   deg      = (int*)(ws + o);   o += (size_t)N_NODES * 4;
    int*   off      = (int*)(ws + o);   o += (size_t)N_NODES * 4;
    int*   cursor   = (int*)(ws + o);   o += (size_t)N_NODES * 4;
    int*   csum     = (int*)(ws + o);   o += 128 * 4;
    int*   src_sorted  = (int*)(ws + o);   o += (size_t)N_EDGES * 4;
    float* e1_sorted   = (float*)(ws + o); o += (size_t)N_EDGES * 4;
    int*   pos_of_edge = (int*)(ws + o);   o += (size_t)N_EDGES * 4;
    float* e2_sorted   = (float*)(ws + o); o += (size_t)N_EDGES * 4;
    float* mu = out + (size_t)N_NODES * (N_SAMP + 1);

    hipMemsetAsync(deg, 0, (size_t)N_NODES * 4, stream);
    hipMemsetAsync(cursor, 0, (size_t)N_NODES * 4, stream);

    const int EB = (N_EDGES + 255) / 256;
    const int WPN = (N_NODES + 3) / 4;

    k_hist<<<EB, 256, 0, stream>>>(dst, deg);
    k_chunksum<<<NCHUNK, 256, 0, stream>>>(deg, csum);
    k_scan98<<<1, 128, 0, stream>>>(csum);
    k_offsets<<<NCHUNK, 256, 0, stream>>>(deg, csum, off);

    k_gemm1<<<(N_NODES + BM - 1) / BM, 256, 0, stream>>>(X, W1, h);
    k_escore<<<WPN, 256, 0, stream>>>(h, a1_src, a1_dst, es, ed);
    k_scatter<<<EB, 256, 0, stream>>>(src, dst, es, ed, off, cursor,
                                      src_sorted, e1_sorted, pos_of_edge);
    k_agg1<<<WPN, 256, 0, stream>>>(h, off, deg, src_sorted, e1_sorted, h1);

    k_l2<<<WPN, 256, 0, stream>>>(h1, W_mu, amu_src, amu_dst, h2, e2s, e2d);
    k_edge2<<<EB, 256, 0, stream>>>(src, dst, e2s, e2d, pos_of_edge, e2_sorted);
    k_agg2<<<(N_NODES * 16 + 255) / 256, 256, 0, stream>>>(h2, off, deg, src_sorted, e2_sorted, mu);

    k_logits<<<(N_NODES + 7) / 8, 256, 0, stream>>>(mu, input_y, sample_ids, ssw, ssb, out);
}

// Round 3
// 782.984 us; speedup vs baseline: 1.1457x; 1.0528x over previous
//
#include <hip/hip_runtime.h>
#include <math.h>

#define N_NODES 100000
#define N_EDGES 1600000
#define F_IN 256
#define F_HID 128
#define F_LAT 2
#define VOCAB 100000
#define N_SAMP 512
#define SLOPE 0.2f

#define CHUNK 1024
#define NCHUNK ((N_NODES + CHUNK - 1) / CHUNK)   // 98

// ---------------------------------------------------------------- histogram
__global__ void k_hist(const int* __restrict__ dst, int* __restrict__ deg) {
    int e = blockIdx.x * blockDim.x + threadIdx.x;
    if (e < N_EDGES) atomicAdd(&deg[dst[e]], 1);
}

// ---------------------------------------------------------------- scan
__global__ void k_chunksum(const int* __restrict__ deg, int* __restrict__ csum) {
    __shared__ int s[256];
    int b = blockIdx.x, t = threadIdx.x;
    int base = b * CHUNK, v = 0;
    for (int i = t; i < CHUNK; i += 256) {
        int idx = base + i;
        if (idx < N_NODES) v += deg[idx];
    }
    s[t] = v; __syncthreads();
    for (int d = 128; d > 0; d >>= 1) { if (t < d) s[t] += s[t + d]; __syncthreads(); }
    if (t == 0) csum[b] = s[0];
}

__global__ void k_scan98(int* __restrict__ csum) {
    __shared__ int s[128];
    int t = threadIdx.x;
    int v = (t < NCHUNK) ? csum[t] : 0;
    s[t] = v; __syncthreads();
    for (int d = 1; d < 128; d <<= 1) {
        int u = (t >= d) ? s[t - d] : 0;
        __syncthreads();
        s[t] += u;
        __syncthreads();
    }
    if (t < NCHUNK) csum[t] = s[t] - v;   // exclusive prefix
}

__global__ void k_offsets(const int* __restrict__ deg, const int* __restrict__ csum,
                          int* __restrict__ off) {
    __shared__ int sd[CHUNK];
    __shared__ int ss[256];
    int b = blockIdx.x, t = threadIdx.x, base = b * CHUNK;
    for (int i = t; i < CHUNK; i += 256) {
        int idx = base + i;
        sd[i] = (idx < N_NODES) ? deg[idx] : 0;
    }
    __syncthreads();
    int l0 = sd[t * 4], l1 = sd[t * 4 + 1], l2 = sd[t * 4 + 2], l3 = sd[t * 4 + 3];
    int tsum = l0 + l1 + l2 + l3;
    ss[t] = tsum; __syncthreads();
    for (int d = 1; d < 256; d <<= 1) {
        int v = 0;
        if (t >= d) v = ss[t - d];
        __syncthreads();
        ss[t] += v;
        __syncthreads();
    }
    int excl = ss[t] - tsum + csum[b];
    int p0 = excl, p1 = p0 + l0, p2 = p1 + l1, p3 = p2 + l2;
    int idx = base + t * 4;
    if (idx     < N_NODES) off[idx]     = p0;
    if (idx + 1 < N_NODES) off[idx + 1] = p1;
    if (idx + 2 < N_NODES) off[idx + 2] = p2;
    if (idx + 3 < N_NODES) off[idx + 3] = p3;
}

// ---------------------------------------------------------------- GEMM1: h = X @ W1 (+fused es/ed epilogue)
// BM=64 rows/block (grid 1563 = 6.1 blocks/CU). Microtile 4 rows x 8 cols with
// STRIDED column ownership col = tx + 16*c:
//   B-read Ws[kk][tx+16c]: 16 consecutive addrs x4 broadcast -> 0 bank conflicts
//   A-read Xs[ty*4+r][kk]: 4 addrs (banks +4 apart) x16 broadcast -> 0 conflicts
#define BM 64
#define BK 32
__launch_bounds__(256)
__global__ void k_gemm1(const float* __restrict__ X, const float* __restrict__ W,
                        const float* __restrict__ a_src, const float* __restrict__ a_dst,
                        float* __restrict__ h, float* __restrict__ es, float* __restrict__ ed) {
    __shared__ float Xs[BM][BK + 1];      // 64 x 33
    __shared__ float Ws[BK][F_HID + 4];   // 32 x 132
    int tid = threadIdx.x;
    int tx = tid & 15;        // owns cols tx + 16*c
    int ty = tid >> 4;        // owns rows ty*4 + r
    int row0 = blockIdx.x * BM;

    float acc[4][8];
#pragma unroll
    for (int r = 0; r < 4; r++)
#pragma unroll
        for (int c = 0; c < 8; c++) acc[r][c] = 0.f;

    for (int kb = 0; kb < F_IN; kb += BK) {
#pragma unroll
        for (int i = 0; i < 2; i++) {           // X tile 64x32 = 512 float4
            int idx = tid + i * 256;
            int r = idx >> 3;
            int kk = (idx & 7) << 2;
            int grow = row0 + r;
            float4 v = make_float4(0.f, 0.f, 0.f, 0.f);
            if (grow < N_NODES) v = *(const float4*)&X[(size_t)grow * F_IN + kb + kk];
            Xs[r][kk] = v.x; Xs[r][kk + 1] = v.y; Xs[r][kk + 2] = v.z; Xs[r][kk + 3] = v.w;
        }
#pragma unroll
        for (int i = 0; i < 4; i++) {           // W tile 32x128 = 1024 float4
            int idx = tid + i * 256;
            int kr = idx >> 5;
            int c = (idx & 31) << 2;
            float4 v = *(const float4*)&W[(size_t)(kb + kr) * F_HID + c];
            Ws[kr][c] = v.x; Ws[kr][c + 1] = v.y; Ws[kr][c + 2] = v.z; Ws[kr][c + 3] = v.w;
        }
        __syncthreads();
#pragma unroll
        for (int kk = 0; kk < BK; kk++) {
            float a[4], bb[8];
#pragma unroll
            for (int r = 0; r < 4; r++) a[r] = Xs[ty * 4 + r][kk];
#pragma unroll
            for (int c = 0; c < 8; c++) bb[c] = Ws[kk][tx + 16 * c];
#pragma unroll
            for (int r = 0; r < 4; r++)
#pragma unroll
                for (int c = 0; c < 8; c++) acc[r][c] = fmaf(a[r], bb[c], acc[r][c]);
        }
        __syncthreads();
    }

    // preload attention vectors for fused escore epilogue
    float asr[8], adr[8];
#pragma unroll
    for (int c = 0; c < 8; c++) { asr[c] = a_src[tx + 16 * c]; adr[c] = a_dst[tx + 16 * c]; }

#pragma unroll
    for (int r = 0; r < 4; r++) {
        int grow = row0 + ty * 4 + r;
        // h store (lanes with same ty write 16 consecutive floats per c)
        if (grow < N_NODES) {
            float* hp = h + (size_t)grow * F_HID + tx;
#pragma unroll
            for (int c = 0; c < 8; c++) hp[16 * c] = acc[r][c];
        }
        // fused es/ed: reduce acc[r][.]*a over the 16 tx lanes
        float sv = 0.f, dv = 0.f;
#pragma unroll
        for (int c = 0; c < 8; c++) { sv = fmaf(acc[r][c], asr[c], sv); dv = fmaf(acc[r][c], adr[c], dv); }
#pragma unroll
        for (int o = 8; o; o >>= 1) { sv += __shfl_xor(sv, o, 16); dv += __shfl_xor(dv, o, 16); }
        if (tx == 0 && grow < N_NODES) { es[grow] = sv; ed[grow] = dv; }
    }
}

// ---------------------------------------------------------------- scatter into CSR + leaky_relu score
__global__ void k_scatter(const int* __restrict__ src, const int* __restrict__ dst,
                          const float* __restrict__ es, const float* __restrict__ ed,
                          const int* __restrict__ off, int* __restrict__ cursor,
                          int* __restrict__ src_sorted, float* __restrict__ e1_sorted) {
    int e = blockIdx.x * blockDim.x + threadIdx.x;
    if (e >= N_EDGES) return;
    int s = src[e], d = dst[e];
    float x = es[s] + ed[d];
    float ev = (x >= 0.f) ? x : SLOPE * x;
    int pos = off[d] + atomicAdd(&cursor[d], 1);
    src_sorted[pos] = s;
    e1_sorted[pos] = ev;
}

// ---------------------------------------------------------------- layer1 aggregation (wave/node)
__global__ void k_agg1(const float* __restrict__ h, const int* __restrict__ off,
                       const int* __restrict__ deg, const int* __restrict__ src_sorted,
                       const float* __restrict__ e1_sorted, float* __restrict__ h1) {
    int node = blockIdx.x * (blockDim.x >> 6) + (threadIdx.x >> 6);
    int lane = threadIdx.x & 63;
    if (node >= N_NODES) return;
    int start = off[node], n = deg[node];
    const int* sp = src_sorted + start;
    const float* ep = e1_sorted + start;

    float m = -INFINITY;
    for (int i = lane; i < n; i += 64) m = fmaxf(m, ep[i]);
#pragma unroll
    for (int o = 32; o; o >>= 1) m = fmaxf(m, __shfl_xor(m, o));

    const float* hb = h + 2 * lane;
    float a0 = 0.f, a1 = 0.f, ssum = 0.f;
    int i = 0;
    for (; i + 4 <= n; i += 4) {
        int s0 = sp[i], s1 = sp[i + 1], s2 = sp[i + 2], s3 = sp[i + 3];
        float w0 = __expf(ep[i] - m);
        float w1 = __expf(ep[i + 1] - m);
        float w2 = __expf(ep[i + 2] - m);
        float w3 = __expf(ep[i + 3] - m);
        float2 r0 = *(const float2*)(hb + (size_t)s0 * F_HID);
        float2 r1 = *(const float2*)(hb + (size_t)s1 * F_HID);
        float2 r2 = *(const float2*)(hb + (size_t)s2 * F_HID);
        float2 r3 = *(const float2*)(hb + (size_t)s3 * F_HID);
        ssum += (w0 + w1) + (w2 + w3);
        a0 = fmaf(w0, r0.x, a0); a1 = fmaf(w0, r0.y, a1);
        a0 = fmaf(w1, r1.x, a0); a1 = fmaf(w1, r1.y, a1);
        a0 = fmaf(w2, r2.x, a0); a1 = fmaf(w2, r2.y, a1);
        a0 = fmaf(w3, r3.x, a0); a1 = fmaf(w3, r3.y, a1);
    }
    for (; i < n; i++) {
        int s = sp[i];
        float w = __expf(ep[i] - m);
        float2 r = *(const float2*)(hb + (size_t)s * F_HID);
        ssum += w;
        a0 = fmaf(w, r.x, a0); a1 = fmaf(w, r.y, a1);
    }
    float inv = 1.f / fmaxf(ssum, 1e-16f);
    float2 outv = {fmaxf(a0 * inv, 0.f), fmaxf(a1 * inv, 0.f)};   // fused relu
    *(float2*)(h1 + (size_t)node * F_HID + 2 * lane) = outv;
}

// ---------------------------------------------------------------- layer2 GEMV -> packed (mu0, mu1, e2s, e2d)
__global__ void k_l2(const float* __restrict__ h1, const float* __restrict__ W_mu,
                     const float* __restrict__ amu_src, const float* __restrict__ amu_dst,
                     float4* __restrict__ n4) {
    int node = blockIdx.x * (blockDim.x >> 6) + (threadIdx.x >> 6);
    int lane = threadIdx.x & 63;
    if (node >= N_NODES) return;
    const float* hr = h1 + (size_t)node * F_HID;
    float x0 = hr[lane], x1 = hr[lane + 64];
    float p0 = x0 * W_mu[lane * 2] + x1 * W_mu[(lane + 64) * 2];
    float p1 = x0 * W_mu[lane * 2 + 1] + x1 * W_mu[(lane + 64) * 2 + 1];
#pragma unroll
    for (int o = 32; o; o >>= 1) { p0 += __shfl_down(p0, o); p1 += __shfl_down(p1, o); }
    if (lane == 0) {
        float4 v;
        v.x = p0;
        v.y = p1;
        v.z = p0 * amu_src[0] + p1 * amu_src[1];
        v.w = p0 * amu_dst[0] + p1 * amu_dst[1];
        n4[node] = v;
    }
}

// ---------------------------------------------------------------- layer2 aggregation, scores computed inline
__global__ void k_agg2(const float4* __restrict__ n4, const int* __restrict__ off,
                       const int* __restrict__ deg, const int* __restrict__ src_sorted,
                       float* __restrict__ mu_out) {
    int node = blockIdx.x * (blockDim.x >> 4) + (threadIdx.x >> 4);
    int lane = threadIdx.x & 15;
    if (node >= N_NODES) return;
    int start = off[node], n = deg[node];
    const int* sp = src_sorted + start;
    float edn = n4[node].w;                    // e2d[dst] broadcast
    float m = -INFINITY;
    for (int i = lane; i < n; i += 16) {
        float x = n4[sp[i]].z + edn;
        m = fmaxf(m, (x >= 0.f) ? x : SLOPE * x);
    }
#pragma unroll
    for (int o = 8; o; o >>= 1) m = fmaxf(m, __shfl_xor(m, o, 16));
    float s = 0.f, a0 = 0.f, a1 = 0.f;
    for (int i = lane; i < n; i += 16) {
        float4 v = n4[sp[i]];
        float x = v.z + edn;
        x = (x >= 0.f) ? x : SLOPE * x;
        float w = __expf(x - m);
        s += w;
        a0 = fmaf(w, v.x, a0);
        a1 = fmaf(w, v.y, a1);
    }
#pragma unroll
    for (int o = 8; o; o >>= 1) {
        s  += __shfl_xor(s, o, 16);
        a0 += __shfl_xor(a0, o, 16);
        a1 += __shfl_xor(a1, o, 16);
    }
    if (lane == 0) {
        float inv = 1.f / fmaxf(s, 1e-16f);
        float2 v = {a0 * inv, a1 * inv};
        *(float2*)(mu_out + node * 2) = v;
    }
}

// ---------------------------------------------------------------- sampled-softmax logits
__global__ void k_logits(const float* __restrict__ mu, const int* __restrict__ input_y,
                         const int* __restrict__ sample_ids, const float* __restrict__ ssw,
                         const float* __restrict__ ssb, float* __restrict__ out) {
    __shared__ float sw0[N_SAMP], sw1[N_SAMP], sb[N_SAMP];
    int t = threadIdx.x;
    for (int i = t; i < N_SAMP; i += blockDim.x) {
        int sid = sample_ids[i];
        sw0[i] = ssw[sid * 2];
        sw1[i] = ssw[sid * 2 + 1];
        sb[i] = ssb[sid];
    }
    __syncthreads();
    int n0 = blockIdx.x * 8;
    for (int k = 0; k < 8; k++) {
        int node = n0 + k;
        if (node >= N_NODES) break;
        float m0 = mu[node * 2], m1 = mu[node * 2 + 1];
        float* orow = out + (size_t)node * (N_SAMP + 1);
        for (int j = t; j < N_SAMP + 1; j += blockDim.x) {
            float v;
            if (j == 0) {
                int y = input_y[node];
                v = m0 * ssw[y * 2] + m1 * ssw[y * 2 + 1] + ssb[y];
            } else {
                v = m0 * sw0[j - 1] + m1 * sw1[j - 1] + sb[j - 1];
            }
            orow[j] = v;
        }
    }
}

// ================================================================ launch
extern "C" void kernel_launch(void* const* d_in, const int* in_sizes, int n_in,
                              void* d_out, int out_size, void* d_ws, size_t ws_size,
                              hipStream_t stream) {
    const float* X          = (const float*)d_in[0];
    const int*   input_y    = (const int*)d_in[2];
    const int*   edge_index = (const int*)d_in[3];
    const int*   sample_ids = (const int*)d_in[4];
    const float* W1         = (const float*)d_in[5];
    const float* a1_src     = (const float*)d_in[6];
    const float* a1_dst     = (const float*)d_in[7];
    const float* W_mu       = (const float*)d_in[8];
    const float* amu_src    = (const float*)d_in[9];
    const float* amu_dst    = (const float*)d_in[10];
    const float* ssw        = (const float*)d_in[14];
    const float* ssb        = (const float*)d_in[15];
    const int* src = edge_index;
    const int* dst = edge_index + N_EDGES;
    float* out = (float*)d_out;

    char* ws = (char*)d_ws;
    size_t o = 0;
    float* h        = (float*)(ws + o); o += (size_t)N_NODES * F_HID * 4;
    float* h1       = (float*)(ws + o); o += (size_t)N_NODES * F_HID * 4;
    float* es       = (float*)(ws + o); o += (size_t)N_NODES * 4;
    float* ed       = (float*)(ws + o); o += (size_t)N_NODES * 4;
    float4* n4      = (float4*)(ws + o); o += (size_t)N_NODES * 16;
    int*   deg      = (int*)(ws + o);   o += (size_t)N_NODES * 4;
    int*   off      = (int*)(ws + o);   o += (size_t)N_NODES * 4;
    int*   cursor   = (int*)(ws + o);   o += (size_t)N_NODES * 4;
    int*   csum     = (int*)(ws + o);   o += 128 * 4;
    int*   src_sorted  = (int*)(ws + o);   o += (size_t)N_EDGES * 4;
    float* e1_sorted   = (float*)(ws + o); o += (size_t)N_EDGES * 4;
    float* mu = out + (size_t)N_NODES * (N_SAMP + 1);

    hipMemsetAsync(deg, 0, (size_t)N_NODES * 4, stream);
    hipMemsetAsync(cursor, 0, (size_t)N_NODES * 4, stream);

    const int EB = (N_EDGES + 255) / 256;
    const int WPN = (N_NODES + 3) / 4;

    k_hist<<<EB, 256, 0, stream>>>(dst, deg);
    k_chunksum<<<NCHUNK, 256, 0, stream>>>(deg, csum);
    k_scan98<<<1, 128, 0, stream>>>(csum);
    k_offsets<<<NCHUNK, 256, 0, stream>>>(deg, csum, off);

    k_gemm1<<<(N_NODES + BM - 1) / BM, 256, 0, stream>>>(X, W1, a1_src, a1_dst, h, es, ed);
    k_scatter<<<EB, 256, 0, stream>>>(src, dst, es, ed, off, cursor, src_sorted, e1_sorted);
    k_agg1<<<WPN, 256, 0, stream>>>(h, off, deg, src_sorted, e1_sorted, h1);

    k_l2<<<WPN, 256, 0, stream>>>(h1, W_mu, amu_src, amu_dst, n4);
    k_agg2<<<(N_NODES * 16 + 255) / 256, 256, 0, stream>>>(n4, off, deg, src_sorted, mu);

    k_logits<<<(N_NODES + 7) / 8, 256, 0, stream>>>(mu, input_y, sample_ids, ssw, ssb, out);
}